// Round 20
// baseline (330.394 us; speedup 1.0000x reference)
//
#include <hip/hip_runtime.h>
#include <math.h>

#define D 128

typedef unsigned int u32;
typedef unsigned short u16;
typedef __attribute__((ext_vector_type(8))) short bf16x8;   // 8 bf16 (4 VGPRs)
typedef __attribute__((ext_vector_type(4))) float f32x4;    // MFMA C/D

__device__ __forceinline__ u32 rotl32(u32 x, int r){ return (x<<r) | (x>>(32-r)); }

__device__ __forceinline__ u16 f2bf(float x){                // round-to-nearest-even
  u32 u = __float_as_uint(x);
  return (u16)((u + 0x7fffu + ((u >> 16) & 1u)) >> 16);
}
__device__ __forceinline__ float bf2f(u16 h){ return __uint_as_float(((u32)h) << 16); }

// eps = jax.random.normal(jax.random.key(42), ...), element m (row-major flat).
// Threefry PARTITIONABLE: counter (0,m), key (0,42); bits = x0^x1.  [verified R3]
__device__ __forceinline__ float jax_normal_part_xor(u32 m){
  const u32 ks0 = 0u, ks1 = 42u, ks2 = 0x1BD11BF0u;
  u32 x0 = 0u + ks0;
  u32 x1 = m  + ks1;
  #define TF_R4(a,b,c,d) \
    x0 += x1; x1 = rotl32(x1,(a)); x1 ^= x0; \
    x0 += x1; x1 = rotl32(x1,(b)); x1 ^= x0; \
    x0 += x1; x1 = rotl32(x1,(c)); x1 ^= x0; \
    x0 += x1; x1 = rotl32(x1,(d)); x1 ^= x0;
  TF_R4(13,15,26,6)   x0 += ks1; x1 += ks2 + 1u;
  TF_R4(17,29,16,24)  x0 += ks2; x1 += ks0 + 2u;
  TF_R4(13,15,26,6)   x0 += ks0; x1 += ks1 + 3u;
  TF_R4(17,29,16,24)  x0 += ks1; x1 += ks2 + 4u;
  TF_R4(13,15,26,6)   x0 += ks2; x1 += ks0 + 5u;
  #undef TF_R4
  u32 bits = x0 ^ x1;
  float f = __uint_as_float((bits >> 9) | 0x3F800000u) - 1.0f;
  const float LO = -0.99999994f;
  float u = fmaxf(LO, f * 2.0f + LO);
  float w = -__logf(fmaf(-u, u, 1.0f));       // = -log(1-u^2)
  float p;
  if (w < 5.0f){
    w -= 2.5f;
    p =  2.81022636e-08f;
    p = fmaf(p, w,  3.43273939e-07f);
    p = fmaf(p, w, -3.5233877e-06f);
    p = fmaf(p, w, -4.39150654e-06f);
    p = fmaf(p, w,  0.00021858087f);
    p = fmaf(p, w, -0.00125372503f);
    p = fmaf(p, w, -0.00417768164f);
    p = fmaf(p, w,  0.246640727f);
    p = fmaf(p, w,  1.50140941f);
  } else {
    w = sqrtf(w) - 3.0f;
    p = -0.000200214257f;
    p = fmaf(p, w,  0.000100950558f);
    p = fmaf(p, w,  0.00134934322f);
    p = fmaf(p, w, -0.00367342844f);
    p = fmaf(p, w,  0.00573950773f);
    p = fmaf(p, w, -0.0076224613f);
    p = fmaf(p, w,  0.00943887047f);
    p = fmaf(p, w,  1.00167406f);
    p = fmaf(p, w,  2.83297682f);
  }
  return 1.41421354f * (p * u);
}

__device__ __forceinline__ float sigmoidf_(float z){ return 1.0f / (1.0f + __expf(-z)); }

// liveness anchors: pin loaded fragments so the scheduler cannot sink the loads
#define KEEP8(a,b,c,d,e,f,g,h) \
  asm volatile("" : "+v"(a),"+v"(b),"+v"(c),"+v"(d),"+v"(e),"+v"(f),"+v"(g),"+v"(h))

// ---------------- prep: detect + init + wconv + xconv + eps, ONE launch -------
__global__ __launch_bounds__(256) void k_prep(
    const u32* __restrict__ e_u32, int* __restrict__ flag,
    const float* __restrict__ W0, const float* __restrict__ W1,
    const float* __restrict__ W2, const float* __restrict__ W3,
    const float* __restrict__ W4, const float* __restrict__ W5,
    u16* __restrict__ wt,
    const float* __restrict__ x, u32* __restrict__ xb,
    u32* __restrict__ epsb, int* __restrict__ cnt, int n, int nx2){
  const int gid = blockIdx.x*256 + threadIdx.x;
  const int stride = gridDim.x*256;
  if (blockIdx.x == 0){
    __shared__ int s_nz;
    if (threadIdx.x == 0) s_nz = 0;
    __syncthreads();
    if (e_u32[2*threadIdx.x + 1] != 0u) atomicAdd(&s_nz, 1);
    __syncthreads();
    if (threadIdx.x == 0) *flag = (s_nz == 0) ? 1 : 0;
  }
  for (int i = gid; i < n; i += stride) cnt[i] = 0;
  for (int i = gid; i < 6*16384; i += stride){
    int mat = i >> 14, idx = i & 16383;
    const float* W = (mat < 2) ? (mat == 0 ? W0 : W1)
                   : (mat < 4) ? (mat == 2 ? W2 : W3)
                               : (mat == 4 ? W4 : W5);
    int k = idx >> 7, c = idx & 127;
    wt[mat*16384 + c*128 + k] = f2bf(W[idx]);
  }
  for (int i = gid; i < nx2; i += stride){
    float2 v = ((const float2*)x)[i];
    xb[i] = (u32)f2bf(v.x) | ((u32)f2bf(v.y) << 16);
  }
  for (int i = gid; i < nx2; i += stride){       // eps: nx2 = N*64 u32 pairs
    u32 m0 = 2u*(u32)i;
    float e0 = jax_normal_part_xor(m0);
    float e1 = jax_normal_part_xor(m0 + 1u);
    epsb[i] = (u32)f2bf(e0) | ((u32)f2bf(e1) << 16);
  }
}

// ---------------- CSR build ----------------
__global__ void k_norm(const void* __restrict__ eidx, const int* __restrict__ flag,
                       int* __restrict__ src_w, int* __restrict__ dst_w,
                       int* __restrict__ cnt, int e){
  int i = blockIdx.x*256 + threadIdx.x;
  if (i >= e) return;
  int s, d;
  if (*flag){
    const u32* u = (const u32*)eidx;
    s = (int)u[2*(size_t)i];
    d = (int)u[2*((size_t)e + i)];
  } else {
    const int* p = (const int*)eidx;
    s = p[i];
    d = p[e + i];
  }
  src_w[i] = s;
  dst_w[i] = d;
  atomicAdd(&cnt[d], 1);
}

__global__ __launch_bounds__(256) void k_scan1(const int* __restrict__ cnt,
                                               int* __restrict__ rp,
                                               int* __restrict__ bsum, int n){
  __shared__ int sh[256];
  int tid = threadIdx.x, idx = blockIdx.x*256 + tid;
  int v = (idx < n) ? cnt[idx] : 0;
  sh[tid] = v; __syncthreads();
  for (int off = 1; off < 256; off <<= 1){
    int t = (tid >= off) ? sh[tid-off] : 0;
    __syncthreads(); sh[tid] += t; __syncthreads();
  }
  if (idx < n) rp[idx] = sh[tid] - v;
  if (tid == 255) bsum[blockIdx.x] = sh[255];
}

__global__ __launch_bounds__(1024) void k_scan2(int* __restrict__ bsum, int nb){
  __shared__ int sh[1024];
  int tid = threadIdx.x;
  int v = (tid < nb) ? bsum[tid] : 0;
  sh[tid] = v; __syncthreads();
  for (int off = 1; off < 1024; off <<= 1){
    int t = (tid >= off) ? sh[tid-off] : 0;
    __syncthreads(); sh[tid] += t; __syncthreads();
  }
  if (tid < nb) bsum[tid] = sh[tid] - v;
}

__global__ void k_scan3(int* __restrict__ rp, int* __restrict__ cur,
                        const int* __restrict__ bsum, const int* __restrict__ cnt,
                        float* __restrict__ dinv_o, int n, int e){
  int idx = blockIdx.x*256 + threadIdx.x;
  if (idx < n){
    int r = rp[idx] + bsum[blockIdx.x];
    rp[idx] = r; cur[idx] = r;
    dinv_o[idx] = rsqrtf((float)(cnt[idx] + 1));
  }
  if (idx == 0) rp[n] = e;
}

__global__ void k_scatter(const int* __restrict__ src, const int* __restrict__ dst,
                          const float* __restrict__ sc, int* __restrict__ cur,
                          int* __restrict__ col, float* __restrict__ wsrt, int e){
  int i = blockIdx.x*256 + threadIdx.x;
  if (i >= e) return;
  int d = dst[i];
  int p = atomicAdd(&cur[d], 1);
  col[p] = src[i];
  wsrt[p] = sc[i];
}

__global__ void k_deg(const int* __restrict__ rp, const float* __restrict__ wsrt,
                      float* __restrict__ dinv_s, int n){
  int i = blockIdx.x*256 + threadIdx.x;
  if (i >= n) return;
  float s = 1.0f;
  int e0 = rp[i], e1 = rp[i+1];
  for (int j = e0; j < e1; ++j) s += wsrt[j];
  dinv_s[i] = rsqrtf(s);
}

// ---------------- aggregations: one wave per node, 8 gathers in flight --------
__global__ __launch_bounds__(256) void k_agg_dual(
    const u32* __restrict__ xb, const int* __restrict__ rp,
    const int* __restrict__ col, const float* __restrict__ wsrt,
    const float* __restrict__ dinv_s, const float* __restrict__ dinv_o,
    u16* __restrict__ out_s, u16* __restrict__ out_o, int n){
  int wid = (blockIdx.x * 256 + threadIdx.x) >> 6;
  int lane = threadIdx.x & 63;
  if (wid >= n) return;
  float dsv = dinv_s[wid], dov = dinv_o[wid];
  u32 xv = xb[(size_t)wid*64 + lane];
  float xlo = bf2f((u16)(xv & 0xffff)), xhi = bf2f((u16)(xv >> 16));
  float ss = dsv*dsv, oo = dov*dov;
  float2 as = { xlo*ss, xhi*ss };
  float2 ao = { xlo*oo, xhi*oo };
  int e0 = rp[wid], e1 = rp[wid+1];
  for (int base = e0; base < e1; base += 64){
    int cnt = e1 - base; if (cnt > 64) cnt = 64;
    int idx = base + (lane < cnt ? lane : cnt - 1);
    int   sl = col[idx];
    float wl = wsrt[idx];
    float nsl = dinv_s[sl] * wl * dsv;
    float nol = dinv_o[sl] * dov;
    int j = 0;
    for (; j + 8 <= cnt; j += 8){
      int s0=__shfl(sl,j),   s1=__shfl(sl,j+1), s2=__shfl(sl,j+2), s3=__shfl(sl,j+3);
      int s4=__shfl(sl,j+4), s5=__shfl(sl,j+5), s6=__shfl(sl,j+6), s7=__shfl(sl,j+7);
      u32 r0 = xb[(size_t)s0*64 + lane];
      u32 r1 = xb[(size_t)s1*64 + lane];
      u32 r2 = xb[(size_t)s2*64 + lane];
      u32 r3 = xb[(size_t)s3*64 + lane];
      u32 r4 = xb[(size_t)s4*64 + lane];
      u32 r5 = xb[(size_t)s5*64 + lane];
      u32 r6 = xb[(size_t)s6*64 + lane];
      u32 r7 = xb[(size_t)s7*64 + lane];
      float a0=__shfl(nsl,j),   a1=__shfl(nsl,j+1), a2=__shfl(nsl,j+2), a3=__shfl(nsl,j+3);
      float a4=__shfl(nsl,j+4), a5=__shfl(nsl,j+5), a6=__shfl(nsl,j+6), a7=__shfl(nsl,j+7);
      float b0=__shfl(nol,j),   b1=__shfl(nol,j+1), b2=__shfl(nol,j+2), b3=__shfl(nol,j+3);
      float b4=__shfl(nol,j+4), b5=__shfl(nol,j+5), b6=__shfl(nol,j+6), b7=__shfl(nol,j+7);
      float l0=bf2f((u16)(r0&0xffff)), h0=bf2f((u16)(r0>>16));
      float l1=bf2f((u16)(r1&0xffff)), h1=bf2f((u16)(r1>>16));
      float l2=bf2f((u16)(r2&0xffff)), h2=bf2f((u16)(r2>>16));
      float l3=bf2f((u16)(r3&0xffff)), h3=bf2f((u16)(r3>>16));
      float l4=bf2f((u16)(r4&0xffff)), h4=bf2f((u16)(r4>>16));
      float l5=bf2f((u16)(r5&0xffff)), h5=bf2f((u16)(r5>>16));
      float l6=bf2f((u16)(r6&0xffff)), h6=bf2f((u16)(r6>>16));
      float l7=bf2f((u16)(r7&0xffff)), h7=bf2f((u16)(r7>>16));
      as.x = fmaf(a0,l0,as.x); as.y = fmaf(a0,h0,as.y);
      ao.x = fmaf(b0,l0,ao.x); ao.y = fmaf(b0,h0,ao.y);
      as.x = fmaf(a1,l1,as.x); as.y = fmaf(a1,h1,as.y);
      ao.x = fmaf(b1,l1,ao.x); ao.y = fmaf(b1,h1,ao.y);
      as.x = fmaf(a2,l2,as.x); as.y = fmaf(a2,h2,as.y);
      ao.x = fmaf(b2,l2,ao.x); ao.y = fmaf(b2,h2,ao.y);
      as.x = fmaf(a3,l3,as.x); as.y = fmaf(a3,h3,as.y);
      ao.x = fmaf(b3,l3,ao.x); ao.y = fmaf(b3,h3,ao.y);
      as.x = fmaf(a4,l4,as.x); as.y = fmaf(a4,h4,as.y);
      ao.x = fmaf(b4,l4,ao.x); ao.y = fmaf(b4,h4,ao.y);
      as.x = fmaf(a5,l5,as.x); as.y = fmaf(a5,h5,as.y);
      ao.x = fmaf(b5,l5,ao.x); ao.y = fmaf(b5,h5,ao.y);
      as.x = fmaf(a6,l6,as.x); as.y = fmaf(a6,h6,as.y);
      ao.x = fmaf(b6,l6,ao.x); ao.y = fmaf(b6,h6,ao.y);
      as.x = fmaf(a7,l7,as.x); as.y = fmaf(a7,h7,as.y);
      ao.x = fmaf(b7,l7,ao.x); ao.y = fmaf(b7,h7,ao.y);
    }
    for (; j < cnt; ++j){
      int   s0=__shfl(sl,j);
      float a0=__shfl(nsl,j), b0=__shfl(nol,j);
      u32 r0 = xb[(size_t)s0*64 + lane];
      float l0 = bf2f((u16)(r0&0xffff)), h0 = bf2f((u16)(r0>>16));
      as.x = fmaf(a0,l0,as.x); as.y = fmaf(a0,h0,as.y);
      ao.x = fmaf(b0,l0,ao.x); ao.y = fmaf(b0,h0,ao.y);
    }
  }
  ((u32*)out_s)[(size_t)wid*64 + lane] = (u32)f2bf(as.x) | ((u32)f2bf(as.y) << 16);
  ((u32*)out_o)[(size_t)wid*64 + lane] = (u32)f2bf(ao.x) | ((u32)f2bf(ao.y) << 16);
}

__global__ __launch_bounds__(256) void k_agg_one(
    const u16* __restrict__ h, const int* __restrict__ rp,
    const int* __restrict__ col, const float* __restrict__ dinv_o,
    u16* __restrict__ out, int n){
  int wid = (blockIdx.x * 256 + threadIdx.x) >> 6;
  int lane = threadIdx.x & 63;
  if (wid >= n) return;
  const u32* h2 = (const u32*)h;
  float dov = dinv_o[wid];
  u32 hv = h2[(size_t)wid*64 + lane];
  float oo = dov*dov;
  float2 ao = { bf2f((u16)(hv & 0xffff))*oo, bf2f((u16)(hv >> 16))*oo };
  int e0 = rp[wid], e1 = rp[wid+1];
  for (int base = e0; base < e1; base += 64){
    int cnt = e1 - base; if (cnt > 64) cnt = 64;
    int idx = base + (lane < cnt ? lane : cnt - 1);
    int   sl = col[idx];
    float nol = dinv_o[sl] * dov;
    int j = 0;
    for (; j + 8 <= cnt; j += 8){
      int s0=__shfl(sl,j),   s1=__shfl(sl,j+1), s2=__shfl(sl,j+2), s3=__shfl(sl,j+3);
      int s4=__shfl(sl,j+4), s5=__shfl(sl,j+5), s6=__shfl(sl,j+6), s7=__shfl(sl,j+7);
      u32 r0 = h2[(size_t)s0*64 + lane];
      u32 r1 = h2[(size_t)s1*64 + lane];
      u32 r2 = h2[(size_t)s2*64 + lane];
      u32 r3 = h2[(size_t)s3*64 + lane];
      u32 r4 = h2[(size_t)s4*64 + lane];
      u32 r5 = h2[(size_t)s5*64 + lane];
      u32 r6 = h2[(size_t)s6*64 + lane];
      u32 r7 = h2[(size_t)s7*64 + lane];
      float b0=__shfl(nol,j),   b1=__shfl(nol,j+1), b2=__shfl(nol,j+2), b3=__shfl(nol,j+3);
      float b4=__shfl(nol,j+4), b5=__shfl(nol,j+5), b6=__shfl(nol,j+6), b7=__shfl(nol,j+7);
      ao.x = fmaf(b0, bf2f((u16)(r0&0xffff)), ao.x); ao.y = fmaf(b0, bf2f((u16)(r0>>16)), ao.y);
      ao.x = fmaf(b1, bf2f((u16)(r1&0xffff)), ao.x); ao.y = fmaf(b1, bf2f((u16)(r1>>16)), ao.y);
      ao.x = fmaf(b2, bf2f((u16)(r2&0xffff)), ao.x); ao.y = fmaf(b2, bf2f((u16)(r2>>16)), ao.y);
      ao.x = fmaf(b3, bf2f((u16)(r3&0xffff)), ao.x); ao.y = fmaf(b3, bf2f((u16)(r3>>16)), ao.y);
      ao.x = fmaf(b4, bf2f((u16)(r4&0xffff)), ao.x); ao.y = fmaf(b4, bf2f((u16)(r4>>16)), ao.y);
      ao.x = fmaf(b5, bf2f((u16)(r5&0xffff)), ao.x); ao.y = fmaf(b5, bf2f((u16)(r5>>16)), ao.y);
      ao.x = fmaf(b6, bf2f((u16)(r6&0xffff)), ao.x); ao.y = fmaf(b6, bf2f((u16)(r6>>16)), ao.y);
      ao.x = fmaf(b7, bf2f((u16)(r7&0xffff)), ao.x); ao.y = fmaf(b7, bf2f((u16)(r7>>16)), ao.y);
    }
    for (; j < cnt; ++j){
      int   s0=__shfl(sl,j);
      float b0=__shfl(nol,j);
      u32 r0 = h2[(size_t)s0*64 + lane];
      ao.x = fmaf(b0, bf2f((u16)(r0&0xffff)), ao.x); ao.y = fmaf(b0, bf2f((u16)(r0>>16)), ao.y);
    }
  }
  ((u32*)out)[(size_t)wid*64 + lane] = (u32)f2bf(ao.x) | ((u32)f2bf(ao.y) << 16);
}

// ---------------- MFMA GEMMs: loads pinned in-flight via asm anchors ----------
// R18 lesson: scheduler sinks loads to uses regardless of launch_bounds.
// KEEP8 anchors after the load block force every fragment live before the
// first MFMA -> all 48 loads in flight at once (true MLP test).
// Frags (16x16x32): A row=lane&15, k=(lane>>4)*8+j ; B col=lane&15 (Wt[col][k]);
// C/D col=lane&15, row=(lane>>4)*4+reg.

__global__ __launch_bounds__(256, 1) void k_mfma_act2(
    const u16* __restrict__ A0, const u16* __restrict__ Wt0, const float* __restrict__ b0,
    const u16* __restrict__ A1, const u16* __restrict__ Wt1, const float* __restrict__ b1,
    const float* __restrict__ temb, const int* __restrict__ t_ptr,
    u16* __restrict__ out0, u16* __restrict__ out1, int n){
  const int sl = blockIdx.y;
  const u16* A  = sl ? A1 : A0;
  const u16* Wt = sl ? Wt1 : Wt0;
  const float* b = sl ? b1 : b0;
  u16* out = sl ? out1 : out0;
  const int tid = threadIdx.x;
  const int lane = tid & 63, wave = tid >> 6;
  const int lr = lane & 15, lg = lane >> 4;
  const int row0 = blockIdx.x * 16;
  int rowf = row0 + lr;
  int rowc = rowf < n ? rowf : n - 1;
  const char* Arow = (const char*)A + (size_t)rowc*256;
  const char* Wb   = (const char*)Wt + (wave*32 + lr)*256 + lg*16;
  bf16x8 af0 = *(const bf16x8*)(Arow + 0*64 + lg*16);
  bf16x8 af1 = *(const bf16x8*)(Arow + 1*64 + lg*16);
  bf16x8 af2 = *(const bf16x8*)(Arow + 2*64 + lg*16);
  bf16x8 af3 = *(const bf16x8*)(Arow + 3*64 + lg*16);
  bf16x8 w00 = *(const bf16x8*)(Wb + 0*4096 + 0*64);
  bf16x8 w01 = *(const bf16x8*)(Wb + 0*4096 + 1*64);
  bf16x8 w02 = *(const bf16x8*)(Wb + 0*4096 + 2*64);
  bf16x8 w03 = *(const bf16x8*)(Wb + 0*4096 + 3*64);
  bf16x8 w10 = *(const bf16x8*)(Wb + 1*4096 + 0*64);
  bf16x8 w11 = *(const bf16x8*)(Wb + 1*4096 + 1*64);
  bf16x8 w12 = *(const bf16x8*)(Wb + 1*4096 + 2*64);
  bf16x8 w13 = *(const bf16x8*)(Wb + 1*4096 + 3*64);
  KEEP8(af0, af1, af2, af3, w00, w01, w02, w03);
  KEEP8(w10, w11, w12, w13, af0, af1, af2, af3);
  f32x4 z = {0.f,0.f,0.f,0.f};
  f32x4 acc0 = z, acc1 = z;
  acc0 = __builtin_amdgcn_mfma_f32_16x16x32_bf16(af0, w00, acc0, 0,0,0);
  acc0 = __builtin_amdgcn_mfma_f32_16x16x32_bf16(af1, w01, acc0, 0,0,0);
  acc0 = __builtin_amdgcn_mfma_f32_16x16x32_bf16(af2, w02, acc0, 0,0,0);
  acc0 = __builtin_amdgcn_mfma_f32_16x16x32_bf16(af3, w03, acc0, 0,0,0);
  acc1 = __builtin_amdgcn_mfma_f32_16x16x32_bf16(af0, w10, acc1, 0,0,0);
  acc1 = __builtin_amdgcn_mfma_f32_16x16x32_bf16(af1, w11, acc1, 0,0,0);
  acc1 = __builtin_amdgcn_mfma_f32_16x16x32_bf16(af2, w12, acc1, 0,0,0);
  acc1 = __builtin_amdgcn_mfma_f32_16x16x32_bf16(af3, w13, acc1, 0,0,0);
  int t = sl ? *t_ptr : 0;
  int rbase = row0 + (lg << 2);
  f32x4 accs[2] = {acc0, acc1};
  #pragma unroll
  for (int cf = 0; cf < 2; ++cf){
    int colw = wave*32 + cf*16 + lr;
    float bb = b[colw];
    float tt = sl ? temb[t*128 + colw] : 0.f;
    #pragma unroll
    for (int r = 0; r < 4; ++r){
      int row = rbase + r;
      if (row < n)
        out[(size_t)row*128 + colw] = f2bf(fmaxf(accs[cf][r] + bb, 0.f) + tt);
    }
  }
}

__global__ __launch_bounds__(256, 1) void k_mfma_quad(
    const u16* __restrict__ Apr, const u16* __restrict__ Aen,
    const u16* __restrict__ Wtpm, const float* __restrict__ bpm,
    const u16* __restrict__ Wtps, const float* __restrict__ bps,
    const u16* __restrict__ Wtmu, const float* __restrict__ bmu,
    const u16* __restrict__ Wtsd, const float* __restrict__ bsd,
    const u32* __restrict__ epsb,
    float* __restrict__ conf, float* __restrict__ pblk, int n){
  const int tid = threadIdx.x;
  const int lane = tid & 63, wave = tid >> 6;
  const int lr = lane & 15, lg = lane >> 4;
  const int row0 = blockIdx.x * 16;
  int rowf = row0 + lr;
  int rowc = rowf < n ? rowf : n - 1;
  const char* Ap = (const char*)Apr + (size_t)rowc*256;
  const char* Ae = (const char*)Aen + (size_t)rowc*256;
  const int wcb = (wave*32 + lr)*256 + lg*16;
  const char* Wpm = (const char*)Wtpm + wcb;
  const char* Wps = (const char*)Wtps + wcb;
  const char* Wmu = (const char*)Wtmu + wcb;
  const char* Wsd = (const char*)Wtsd + wcb;
  int rbase = row0 + (lg << 2);
  // ---- issue EVERY load, then pin with anchors (true 48-deep MLP) ----
  int er0 = rbase + 0; if (er0 >= n) er0 = n - 1;
  int er1 = rbase + 1; if (er1 >= n) er1 = n - 1;
  int er2 = rbase + 2; if (er2 >= n) er2 = n - 1;
  int er3 = rbase + 3; if (er3 >= n) er3 = n - 1;
  int ec0 = (wave*32 + 0*16 + lr) >> 1, ec1 = (wave*32 + 1*16 + lr) >> 1;
  u32 ew00 = epsb[(size_t)er0*64 + ec0];
  u32 ew01 = epsb[(size_t)er1*64 + ec0];
  u32 ew02 = epsb[(size_t)er2*64 + ec0];
  u32 ew03 = epsb[(size_t)er3*64 + ec0];
  u32 ew10 = epsb[(size_t)er0*64 + ec1];
  u32 ew11 = epsb[(size_t)er1*64 + ec1];
  u32 ew12 = epsb[(size_t)er2*64 + ec1];
  u32 ew13 = epsb[(size_t)er3*64 + ec1];
  bf16x8 ap0 = *(const bf16x8*)(Ap + 0*64 + lg*16);
  bf16x8 ap1 = *(const bf16x8*)(Ap + 1*64 + lg*16);
  bf16x8 ap2 = *(const bf16x8*)(Ap + 2*64 + lg*16);
  bf16x8 ap3 = *(const bf16x8*)(Ap + 3*64 + lg*16);
  bf16x8 ae0 = *(const bf16x8*)(Ae + 0*64 + lg*16);
  bf16x8 ae1 = *(const bf16x8*)(Ae + 1*64 + lg*16);
  bf16x8 ae2 = *(const bf16x8*)(Ae + 2*64 + lg*16);
  bf16x8 ae3 = *(const bf16x8*)(Ae + 3*64 + lg*16);
  bf16x8 pm00 = *(const bf16x8*)(Wpm + 0*4096 + 0*64);
  bf16x8 pm01 = *(const bf16x8*)(Wpm + 0*4096 + 1*64);
  bf16x8 pm02 = *(const bf16x8*)(Wpm + 0*4096 + 2*64);
  bf16x8 pm03 = *(const bf16x8*)(Wpm + 0*4096 + 3*64);
  bf16x8 pm10 = *(const bf16x8*)(Wpm + 1*4096 + 0*64);
  bf16x8 pm11 = *(const bf16x8*)(Wpm + 1*4096 + 1*64);
  bf16x8 pm12 = *(const bf16x8*)(Wpm + 1*4096 + 2*64);
  bf16x8 pm13 = *(const bf16x8*)(Wpm + 1*4096 + 3*64);
  bf16x8 ps00 = *(const bf16x8*)(Wps + 0*4096 + 0*64);
  bf16x8 ps01 = *(const bf16x8*)(Wps + 0*4096 + 1*64);
  bf16x8 ps02 = *(const bf16x8*)(Wps + 0*4096 + 2*64);
  bf16x8 ps03 = *(const bf16x8*)(Wps + 0*4096 + 3*64);
  bf16x8 ps10 = *(const bf16x8*)(Wps + 1*4096 + 0*64);
  bf16x8 ps11 = *(const bf16x8*)(Wps + 1*4096 + 1*64);
  bf16x8 ps12 = *(const bf16x8*)(Wps + 1*4096 + 2*64);
  bf16x8 ps13 = *(const bf16x8*)(Wps + 1*4096 + 3*64);
  bf16x8 mu00 = *(const bf16x8*)(Wmu + 0*4096 + 0*64);
  bf16x8 mu01 = *(const bf16x8*)(Wmu + 0*4096 + 1*64);
  bf16x8 mu02 = *(const bf16x8*)(Wmu + 0*4096 + 2*64);
  bf16x8 mu03 = *(const bf16x8*)(Wmu + 0*4096 + 3*64);
  bf16x8 mu10 = *(const bf16x8*)(Wmu + 1*4096 + 0*64);
  bf16x8 mu11 = *(const bf16x8*)(Wmu + 1*4096 + 1*64);
  bf16x8 mu12 = *(const bf16x8*)(Wmu + 1*4096 + 2*64);
  bf16x8 mu13 = *(const bf16x8*)(Wmu + 1*4096 + 3*64);
  bf16x8 sd00 = *(const bf16x8*)(Wsd + 0*4096 + 0*64);
  bf16x8 sd01 = *(const bf16x8*)(Wsd + 0*4096 + 1*64);
  bf16x8 sd02 = *(const bf16x8*)(Wsd + 0*4096 + 2*64);
  bf16x8 sd03 = *(const bf16x8*)(Wsd + 0*4096 + 3*64);
  bf16x8 sd10 = *(const bf16x8*)(Wsd + 1*4096 + 0*64);
  bf16x8 sd11 = *(const bf16x8*)(Wsd + 1*4096 + 1*64);
  bf16x8 sd12 = *(const bf16x8*)(Wsd + 1*4096 + 2*64);
  bf16x8 sd13 = *(const bf16x8*)(Wsd + 1*4096 + 3*64);
  // pin everything live before the first MFMA
  KEEP8(ew00, ew01, ew02, ew03, ew10, ew11, ew12, ew13);
  KEEP8(ap0, ap1, ap2, ap3, ae0, ae1, ae2, ae3);
  KEEP8(pm00, pm01, pm02, pm03, pm10, pm11, pm12, pm13);
  KEEP8(ps00, ps01, ps02, ps03, ps10, ps11, ps12, ps13);
  KEEP8(mu00, mu01, mu02, mu03, mu10, mu11, mu12, mu13);
  KEEP8(sd00, sd01, sd02, sd03, sd10, sd11, sd12, sd13);
  f32x4 z = {0.f,0.f,0.f,0.f};
  f32x4 aPM[2], aPS[2], aMU[2], aSD[2];
  #pragma unroll
  for (int i = 0; i < 2; ++i){ aPM[i]=z; aPS[i]=z; aMU[i]=z; aSD[i]=z; }
  aPM[0] = __builtin_amdgcn_mfma_f32_16x16x32_bf16(ap0, pm00, aPM[0], 0,0,0);
  aPM[0] = __builtin_amdgcn_mfma_f32_16x16x32_bf16(ap1, pm01, aPM[0], 0,0,0);
  aPM[0] = __builtin_amdgcn_mfma_f32_16x16x32_bf16(ap2, pm02, aPM[0], 0,0,0);
  aPM[0] = __builtin_amdgcn_mfma_f32_16x16x32_bf16(ap3, pm03, aPM[0], 0,0,0);
  aPM[1] = __builtin_amdgcn_mfma_f32_16x16x32_bf16(ap0, pm10, aPM[1], 0,0,0);
  aPM[1] = __builtin_amdgcn_mfma_f32_16x16x32_bf16(ap1, pm11, aPM[1], 0,0,0);
  aPM[1] = __builtin_amdgcn_mfma_f32_16x16x32_bf16(ap2, pm12, aPM[1], 0,0,0);
  aPM[1] = __builtin_amdgcn_mfma_f32_16x16x32_bf16(ap3, pm13, aPM[1], 0,0,0);
  aPS[0] = __builtin_amdgcn_mfma_f32_16x16x32_bf16(ap0, ps00, aPS[0], 0,0,0);
  aPS[0] = __builtin_amdgcn_mfma_f32_16x16x32_bf16(ap1, ps01, aPS[0], 0,0,0);
  aPS[0] = __builtin_amdgcn_mfma_f32_16x16x32_bf16(ap2, ps02, aPS[0], 0,0,0);
  aPS[0] = __builtin_amdgcn_mfma_f32_16x16x32_bf16(ap3, ps03, aPS[0], 0,0,0);
  aPS[1] = __builtin_amdgcn_mfma_f32_16x16x32_bf16(ap0, ps10, aPS[1], 0,0,0);
  aPS[1] = __builtin_amdgcn_mfma_f32_16x16x32_bf16(ap1, ps11, aPS[1], 0,0,0);
  aPS[1] = __builtin_amdgcn_mfma_f32_16x16x32_bf16(ap2, ps12, aPS[1], 0,0,0);
  aPS[1] = __builtin_amdgcn_mfma_f32_16x16x32_bf16(ap3, ps13, aPS[1], 0,0,0);
  aMU[0] = __builtin_amdgcn_mfma_f32_16x16x32_bf16(ae0, mu00, aMU[0], 0,0,0);
  aMU[0] = __builtin_amdgcn_mfma_f32_16x16x32_bf16(ae1, mu01, aMU[0], 0,0,0);
  aMU[0] = __builtin_amdgcn_mfma_f32_16x16x32_bf16(ae2, mu02, aMU[0], 0,0,0);
  aMU[0] = __builtin_amdgcn_mfma_f32_16x16x32_bf16(ae3, mu03, aMU[0], 0,0,0);
  aMU[1] = __builtin_amdgcn_mfma_f32_16x16x32_bf16(ae0, mu10, aMU[1], 0,0,0);
  aMU[1] = __builtin_amdgcn_mfma_f32_16x16x32_bf16(ae1, mu11, aMU[1], 0,0,0);
  aMU[1] = __builtin_amdgcn_mfma_f32_16x16x32_bf16(ae2, mu12, aMU[1], 0,0,0);
  aMU[1] = __builtin_amdgcn_mfma_f32_16x16x32_bf16(ae3, mu13, aMU[1], 0,0,0);
  aSD[0] = __builtin_amdgcn_mfma_f32_16x16x32_bf16(ae0, sd00, aSD[0], 0,0,0);
  aSD[0] = __builtin_amdgcn_mfma_f32_16x16x32_bf16(ae1, sd01, aSD[0], 0,0,0);
  aSD[0] = __builtin_amdgcn_mfma_f32_16x16x32_bf16(ae2, sd02, aSD[0], 0,0,0);
  aSD[0] = __builtin_amdgcn_mfma_f32_16x16x32_bf16(ae3, sd03, aSD[0], 0,0,0);
  aSD[1] = __builtin_amdgcn_mfma_f32_16x16x32_bf16(ae0, sd10, aSD[1], 0,0,0);
  aSD[1] = __builtin_amdgcn_mfma_f32_16x16x32_bf16(ae1, sd11, aSD[1], 0,0,0);
  aSD[1] = __builtin_amdgcn_mfma_f32_16x16x32_bf16(ae2, sd12, aSD[1], 0,0,0);
  aSD[1] = __builtin_amdgcn_mfma_f32_16x16x32_bf16(ae3, sd13, aSD[1], 0,0,0);
  const float EPS = 1e-9f;
  u32 ew[2][4] = {{ew00, ew01, ew02, ew03}, {ew10, ew11, ew12, ew13}};
  float klsum = 0.f;
  #pragma unroll
  for (int cf = 0; cf < 2; ++cf){
    int colw = wave*32 + cf*16 + lr;
    float bb1 = bpm[colw], bb2 = bps[colw];
    float bb3 = bmu[colw], bb4 = bsd[colw];
    #pragma unroll
    for (int r = 0; r < 4; ++r){
      int row = rbase + r;
      if (row < n){
        size_t m = (size_t)row*128 + colw;
        float pmv = aPM[cf][r] + bb1;
        float psv = sigmoidf_(aPS[cf][r] + bb2);
        float em  = aMU[cf][r] + bb3;
        float es  = sigmoidf_(aSD[cf][r] + bb4);
        float eps = bf2f((u16)((colw & 1) ? (ew[cf][r] >> 16) : (ew[cf][r] & 0xffff)));
        conf[m] = fmaf(eps, es, em);
        float es_e = es + EPS, ps_e = psv + EPS;
        float diff = em - pmv;
        klsum += 2.0f*__logf(ps_e/es_e)
               + (es_e*es_e + diff*diff) / (ps_e*ps_e) - 1.0f;
      }
    }
  }
  #pragma unroll
  for (int off = 32; off > 0; off >>= 1) klsum += __shfl_down(klsum, off);
  __shared__ float wsum[4];
  if ((tid & 63) == 0) wsum[tid >> 6] = klsum;
  __syncthreads();
  if (tid == 0) pblk[blockIdx.x] = wsum[0] + wsum[1] + wsum[2] + wsum[3];
}

__global__ __launch_bounds__(256) void k_finish(const float* __restrict__ pblk, int nb,
                                                float* __restrict__ out0, int n){
  __shared__ double sh[256];
  double s = 0.0;
  for (int i = threadIdx.x; i < nb; i += 256) s += (double)pblk[i];
  sh[threadIdx.x] = s; __syncthreads();
  for (int off = 128; off > 0; off >>= 1){
    if (threadIdx.x < off) sh[threadIdx.x] += sh[threadIdx.x + off];
    __syncthreads();
  }
  if (threadIdx.x == 0) out0[0] = (float)(0.5 * sh[0] / (double)n);
}

// ---------------------------------------------------------------------------
extern "C" void kernel_launch(void* const* d_in, const int* in_sizes, int n_in,
                              void* d_out, int out_size, void* d_ws, size_t ws_size,
                              hipStream_t stream){
  const void*  eidx   = d_in[0];
  const float* x      = (const float*)d_in[1];
  const int*   t_ptr  = (const int*)d_in[2];
  const float* escore = (const float*)d_in[3];
  const float* W_enc = (const float*)d_in[6];  const float* b_enc = (const float*)d_in[7];
  const float* W_mu  = (const float*)d_in[8];  const float* b_mu  = (const float*)d_in[9];
  const float* W_std = (const float*)d_in[10]; const float* b_std = (const float*)d_in[11];
  const float* W_pr  = (const float*)d_in[12]; const float* b_pr  = (const float*)d_in[13];
  const float* W_pm  = (const float*)d_in[14]; const float* b_pm  = (const float*)d_in[15];
  const float* W_ps  = (const float*)d_in[16]; const float* b_ps  = (const float*)d_in[17];
  const float* temb  = (const float*)d_in[18];

  const int N = in_sizes[1] / D;
  const int E = in_sizes[3];

  char* w = (char*)d_ws;
  auto alloc = [&](size_t bytes) -> char* {
    char* p = w; w += (bytes + 255) & ~(size_t)255; return p;
  };
  int*    flag   = (int*)   alloc(256);
  int*    src_w  = (int*)   alloc((size_t)E*4);
  int*    dst_w  = (int*)   alloc((size_t)E*4);
  int*    cnt    = (int*)   alloc((size_t)N*4);
  int*    rp     = (int*)   alloc((size_t)(N+1)*4);
  int*    cur    = (int*)   alloc((size_t)N*4);
  float*  dinv_s = (float*) alloc((size_t)N*4);
  float*  dinv_o = (float*) alloc((size_t)N*4);
  int*    bsum   = (int*)   alloc(1024*4);
  int*    col    = (int*)   alloc((size_t)E*4);
  float*  wsrt   = (float*) alloc((size_t)E*4);
  u16*    wt     = (u16*)   alloc((size_t)6*16384*2);  // 6 transposed bf16 weights
  u32*    XB     = (u32*)   alloc((size_t)N*64*4);     // bf16x2-packed x
  u16*    B1     = (u16*)   alloc((size_t)N*D*2);  // agg_score_x (bf16)
  u16*    B2     = (u16*)   alloc((size_t)N*D*2);  // agg_ones_x -> agg_ones_enc
  u16*    B3     = (u16*)   alloc((size_t)N*D*2);  // enc_t
  u16*    B5     = (u16*)   alloc((size_t)N*D*2);  // prior
  u32*    EPSB   = (u32*)   alloc((size_t)N*64*4); // bf16x2-packed eps
  const int gG16 = (N + 15) / 16;                  // MFMA tiles (16 rows)
  float*  pblk   = (float*) alloc((size_t)gG16*4);
  (void)ws_size; (void)n_in; (void)out_size;

  float* conf = ((float*)d_out) + 1;

  u16* Wt_enc = wt + 0*16384;
  u16* Wt_pr  = wt + 1*16384;
  u16* Wt_pm  = wt + 2*16384;
  u16* Wt_ps  = wt + 3*16384;
  u16* Wt_mu  = wt + 4*16384;
  u16* Wt_std = wt + 5*16384;

  const int gE  = (E + 255) / 256;
  const int gN  = (N + 255) / 256;
  const int gW  = (N * 64 + 255) / 256;

  // prep: detect + init(cnt) + wconv + xconv + eps, one launch (grid-stride)
  k_prep   <<<2048, 256, 0, stream>>>((const u32*)eidx, flag,
                                      W_enc, W_pr, W_pm, W_ps, W_mu, W_std, wt,
                                      x, XB, EPSB, cnt, N, N*64);
  k_norm   <<<gE, 256, 0, stream>>>(eidx, flag, src_w, dst_w, cnt, E);
  k_scan1  <<<gN, 256, 0, stream>>>(cnt, rp, bsum, N);
  k_scan2  <<<1, 1024, 0, stream>>>(bsum, gN);
  k_scan3  <<<gN, 256, 0, stream>>>(rp, cur, bsum, cnt, dinv_o, N, E);
  k_scatter<<<gE, 256, 0, stream>>>(src_w, dst_w, escore, cur, col, wsrt, E);
  k_deg    <<<gN, 256, 0, stream>>>(rp, wsrt, dinv_s, N);

  // agg_sx -> B1 (bf16) ; agg_ox -> B2 (bf16)
  k_agg_dual<<<gW, 256, 0, stream>>>(XB, rp, col, wsrt, dinv_s, dinv_o, B1, B2, N);
  // y=0: enc_t = relu(B1@Wenc+b) -> B3 ; y=1: prior = relu(B2@Wpr+b)+temb -> B5
  k_mfma_act2<<<dim3(gG16,2), 256, 0, stream>>>(B1, Wt_enc, b_enc, B2, Wt_pr, b_pr,
                                                temb, t_ptr, B3, B5, N);
  // agg_oe = A_ones enc_t -> B2 (bf16 gather)
  k_agg_one<<<gW, 256, 0, stream>>>(B3, rp, col, dinv_o, B2, N);
  // pm/ps/em/es + conf + kl partials, fused
  k_mfma_quad<<<gG16, 256, 0, stream>>>(B5, B2, Wt_pm, b_pm, Wt_ps, b_ps,
                                        Wt_mu, b_mu, Wt_std, b_std, EPSB,
                                        conf, pblk, N);
  k_finish<<<1, 256, 0, stream>>>(pblk, gG16, (float*)d_out, N);
}

// Round 21
// 308.763 us; speedup vs baseline: 1.0701x; 1.0701x over previous
//
#include <hip/hip_runtime.h>
#include <math.h>

#define D 128

typedef unsigned int u32;
typedef unsigned short u16;
typedef __attribute__((ext_vector_type(8))) short bf16x8;   // 8 bf16 (4 VGPRs)
typedef __attribute__((ext_vector_type(4))) float f32x4;    // MFMA C/D

__device__ __forceinline__ u32 rotl32(u32 x, int r){ return (x<<r) | (x>>(32-r)); }

__device__ __forceinline__ u16 f2bf(float x){                // round-to-nearest-even
  u32 u = __float_as_uint(x);
  return (u16)((u + 0x7fffu + ((u >> 16) & 1u)) >> 16);
}
__device__ __forceinline__ float bf2f(u16 h){ return __uint_as_float(((u32)h) << 16); }

// eps = jax.random.normal(jax.random.key(42), ...), element m (row-major flat).
// Threefry PARTITIONABLE: counter (0,m), key (0,42); bits = x0^x1.  [verified R3]
__device__ __forceinline__ float jax_normal_part_xor(u32 m){
  const u32 ks0 = 0u, ks1 = 42u, ks2 = 0x1BD11BF0u;
  u32 x0 = 0u + ks0;
  u32 x1 = m  + ks1;
  #define TF_R4(a,b,c,d) \
    x0 += x1; x1 = rotl32(x1,(a)); x1 ^= x0; \
    x0 += x1; x1 = rotl32(x1,(b)); x1 ^= x0; \
    x0 += x1; x1 = rotl32(x1,(c)); x1 ^= x0; \
    x0 += x1; x1 = rotl32(x1,(d)); x1 ^= x0;
  TF_R4(13,15,26,6)   x0 += ks1; x1 += ks2 + 1u;
  TF_R4(17,29,16,24)  x0 += ks2; x1 += ks0 + 2u;
  TF_R4(13,15,26,6)   x0 += ks0; x1 += ks1 + 3u;
  TF_R4(17,29,16,24)  x0 += ks1; x1 += ks2 + 4u;
  TF_R4(13,15,26,6)   x0 += ks2; x1 += ks0 + 5u;
  #undef TF_R4
  u32 bits = x0 ^ x1;
  float f = __uint_as_float((bits >> 9) | 0x3F800000u) - 1.0f;
  const float LO = -0.99999994f;
  float u = fmaxf(LO, f * 2.0f + LO);
  float w = -__logf(fmaf(-u, u, 1.0f));       // = -log(1-u^2)
  float p;
  if (w < 5.0f){
    w -= 2.5f;
    p =  2.81022636e-08f;
    p = fmaf(p, w,  3.43273939e-07f);
    p = fmaf(p, w, -3.5233877e-06f);
    p = fmaf(p, w, -4.39150654e-06f);
    p = fmaf(p, w,  0.00021858087f);
    p = fmaf(p, w, -0.00125372503f);
    p = fmaf(p, w, -0.00417768164f);
    p = fmaf(p, w,  0.246640727f);
    p = fmaf(p, w,  1.50140941f);
  } else {
    w = sqrtf(w) - 3.0f;
    p = -0.000200214257f;
    p = fmaf(p, w,  0.000100950558f);
    p = fmaf(p, w,  0.00134934322f);
    p = fmaf(p, w, -0.00367342844f);
    p = fmaf(p, w,  0.00573950773f);
    p = fmaf(p, w, -0.0076224613f);
    p = fmaf(p, w,  0.00943887047f);
    p = fmaf(p, w,  1.00167406f);
    p = fmaf(p, w,  2.83297682f);
  }
  return 1.41421354f * (p * u);
}

__device__ __forceinline__ float sigmoidf_(float z){ return 1.0f / (1.0f + __expf(-z)); }

// ---------------- prep: detect + init + wconv + xconv + eps, ONE launch -------
__global__ __launch_bounds__(256) void k_prep(
    const u32* __restrict__ e_u32, int* __restrict__ flag,
    const float* __restrict__ W0, const float* __restrict__ W1,
    const float* __restrict__ W2, const float* __restrict__ W3,
    const float* __restrict__ W4, const float* __restrict__ W5,
    u16* __restrict__ wt,
    const float* __restrict__ x, u32* __restrict__ xb,
    u32* __restrict__ epsb, int* __restrict__ cnt, int n, int nx2){
  const int gid = blockIdx.x*256 + threadIdx.x;
  const int stride = gridDim.x*256;
  if (blockIdx.x == 0){
    __shared__ int s_nz;
    if (threadIdx.x == 0) s_nz = 0;
    __syncthreads();
    if (e_u32[2*threadIdx.x + 1] != 0u) atomicAdd(&s_nz, 1);
    __syncthreads();
    if (threadIdx.x == 0) *flag = (s_nz == 0) ? 1 : 0;
  }
  for (int i = gid; i < n; i += stride) cnt[i] = 0;
  for (int i = gid; i < 6*16384; i += stride){
    int mat = i >> 14, idx = i & 16383;
    const float* W = (mat < 2) ? (mat == 0 ? W0 : W1)
                   : (mat < 4) ? (mat == 2 ? W2 : W3)
                               : (mat == 4 ? W4 : W5);
    int k = idx >> 7, c = idx & 127;
    wt[mat*16384 + c*128 + k] = f2bf(W[idx]);
  }
  for (int i = gid; i < nx2; i += stride){
    float2 v = ((const float2*)x)[i];
    xb[i] = (u32)f2bf(v.x) | ((u32)f2bf(v.y) << 16);
  }
  for (int i = gid; i < nx2; i += stride){       // eps: nx2 = N*64 u32 pairs
    u32 m0 = 2u*(u32)i;
    float e0 = jax_normal_part_xor(m0);
    float e1 = jax_normal_part_xor(m0 + 1u);
    epsb[i] = (u32)f2bf(e0) | ((u32)f2bf(e1) << 16);
  }
}

// ---------------- CSR build ----------------
__global__ void k_norm(const void* __restrict__ eidx, const int* __restrict__ flag,
                       int* __restrict__ src_w, int* __restrict__ dst_w,
                       int* __restrict__ cnt, int e){
  int i = blockIdx.x*256 + threadIdx.x;
  if (i >= e) return;
  int s, d;
  if (*flag){
    const u32* u = (const u32*)eidx;
    s = (int)u[2*(size_t)i];
    d = (int)u[2*((size_t)e + i)];
  } else {
    const int* p = (const int*)eidx;
    s = p[i];
    d = p[e + i];
  }
  src_w[i] = s;
  dst_w[i] = d;
  atomicAdd(&cnt[d], 1);
}

__global__ __launch_bounds__(256) void k_scan1(const int* __restrict__ cnt,
                                               int* __restrict__ rp,
                                               int* __restrict__ bsum, int n){
  __shared__ int sh[256];
  int tid = threadIdx.x, idx = blockIdx.x*256 + tid;
  int v = (idx < n) ? cnt[idx] : 0;
  sh[tid] = v; __syncthreads();
  for (int off = 1; off < 256; off <<= 1){
    int t = (tid >= off) ? sh[tid-off] : 0;
    __syncthreads(); sh[tid] += t; __syncthreads();
  }
  if (idx < n) rp[idx] = sh[tid] - v;
  if (tid == 255) bsum[blockIdx.x] = sh[255];
}

__global__ __launch_bounds__(1024) void k_scan2(int* __restrict__ bsum, int nb){
  __shared__ int sh[1024];
  int tid = threadIdx.x;
  int v = (tid < nb) ? bsum[tid] : 0;
  sh[tid] = v; __syncthreads();
  for (int off = 1; off < 1024; off <<= 1){
    int t = (tid >= off) ? sh[tid-off] : 0;
    __syncthreads(); sh[tid] += t; __syncthreads();
  }
  if (tid < nb) bsum[tid] = sh[tid] - v;
}

__global__ void k_scan3(int* __restrict__ rp, int* __restrict__ cur,
                        const int* __restrict__ bsum, const int* __restrict__ cnt,
                        float* __restrict__ dinv_o, int n, int e){
  int idx = blockIdx.x*256 + threadIdx.x;
  if (idx < n){
    int r = rp[idx] + bsum[blockIdx.x];
    rp[idx] = r; cur[idx] = r;
    dinv_o[idx] = rsqrtf((float)(cnt[idx] + 1));
  }
  if (idx == 0) rp[n] = e;
}

__global__ void k_scatter(const int* __restrict__ src, const int* __restrict__ dst,
                          const float* __restrict__ sc, int* __restrict__ cur,
                          int* __restrict__ col, float* __restrict__ wsrt, int e){
  int i = blockIdx.x*256 + threadIdx.x;
  if (i >= e) return;
  int d = dst[i];
  int p = atomicAdd(&cur[d], 1);
  col[p] = src[i];
  wsrt[p] = sc[i];
}

__global__ void k_deg(const int* __restrict__ rp, const float* __restrict__ wsrt,
                      float* __restrict__ dinv_s, int n){
  int i = blockIdx.x*256 + threadIdx.x;
  if (i >= n) return;
  float s = 1.0f;
  int e0 = rp[i], e1 = rp[i+1];
  for (int j = e0; j < e1; ++j) s += wsrt[j];
  dinv_s[i] = rsqrtf(s);
}

// ---------------- aggregations: one wave per node, 8 gathers in flight --------
__global__ __launch_bounds__(256) void k_agg_dual(
    const u32* __restrict__ xb, const int* __restrict__ rp,
    const int* __restrict__ col, const float* __restrict__ wsrt,
    const float* __restrict__ dinv_s, const float* __restrict__ dinv_o,
    u16* __restrict__ out_s, u16* __restrict__ out_o, int n){
  int wid = (blockIdx.x * 256 + threadIdx.x) >> 6;
  int lane = threadIdx.x & 63;
  if (wid >= n) return;
  float dsv = dinv_s[wid], dov = dinv_o[wid];
  u32 xv = xb[(size_t)wid*64 + lane];
  float xlo = bf2f((u16)(xv & 0xffff)), xhi = bf2f((u16)(xv >> 16));
  float ss = dsv*dsv, oo = dov*dov;
  float2 as = { xlo*ss, xhi*ss };
  float2 ao = { xlo*oo, xhi*oo };
  int e0 = rp[wid], e1 = rp[wid+1];
  for (int base = e0; base < e1; base += 64){
    int cnt = e1 - base; if (cnt > 64) cnt = 64;
    int idx = base + (lane < cnt ? lane : cnt - 1);
    int   sl = col[idx];
    float wl = wsrt[idx];
    float nsl = dinv_s[sl] * wl * dsv;
    float nol = dinv_o[sl] * dov;
    int j = 0;
    for (; j + 8 <= cnt; j += 8){
      int s0=__shfl(sl,j),   s1=__shfl(sl,j+1), s2=__shfl(sl,j+2), s3=__shfl(sl,j+3);
      int s4=__shfl(sl,j+4), s5=__shfl(sl,j+5), s6=__shfl(sl,j+6), s7=__shfl(sl,j+7);
      u32 r0 = xb[(size_t)s0*64 + lane];
      u32 r1 = xb[(size_t)s1*64 + lane];
      u32 r2 = xb[(size_t)s2*64 + lane];
      u32 r3 = xb[(size_t)s3*64 + lane];
      u32 r4 = xb[(size_t)s4*64 + lane];
      u32 r5 = xb[(size_t)s5*64 + lane];
      u32 r6 = xb[(size_t)s6*64 + lane];
      u32 r7 = xb[(size_t)s7*64 + lane];
      float a0=__shfl(nsl,j),   a1=__shfl(nsl,j+1), a2=__shfl(nsl,j+2), a3=__shfl(nsl,j+3);
      float a4=__shfl(nsl,j+4), a5=__shfl(nsl,j+5), a6=__shfl(nsl,j+6), a7=__shfl(nsl,j+7);
      float b0=__shfl(nol,j),   b1=__shfl(nol,j+1), b2=__shfl(nol,j+2), b3=__shfl(nol,j+3);
      float b4=__shfl(nol,j+4), b5=__shfl(nol,j+5), b6=__shfl(nol,j+6), b7=__shfl(nol,j+7);
      float l0=bf2f((u16)(r0&0xffff)), h0=bf2f((u16)(r0>>16));
      float l1=bf2f((u16)(r1&0xffff)), h1=bf2f((u16)(r1>>16));
      float l2=bf2f((u16)(r2&0xffff)), h2=bf2f((u16)(r2>>16));
      float l3=bf2f((u16)(r3&0xffff)), h3=bf2f((u16)(r3>>16));
      float l4=bf2f((u16)(r4&0xffff)), h4=bf2f((u16)(r4>>16));
      float l5=bf2f((u16)(r5&0xffff)), h5=bf2f((u16)(r5>>16));
      float l6=bf2f((u16)(r6&0xffff)), h6=bf2f((u16)(r6>>16));
      float l7=bf2f((u16)(r7&0xffff)), h7=bf2f((u16)(r7>>16));
      as.x = fmaf(a0,l0,as.x); as.y = fmaf(a0,h0,as.y);
      ao.x = fmaf(b0,l0,ao.x); ao.y = fmaf(b0,h0,ao.y);
      as.x = fmaf(a1,l1,as.x); as.y = fmaf(a1,h1,as.y);
      ao.x = fmaf(b1,l1,ao.x); ao.y = fmaf(b1,h1,ao.y);
      as.x = fmaf(a2,l2,as.x); as.y = fmaf(a2,h2,as.y);
      ao.x = fmaf(b2,l2,ao.x); ao.y = fmaf(b2,h2,ao.y);
      as.x = fmaf(a3,l3,as.x); as.y = fmaf(a3,h3,as.y);
      ao.x = fmaf(b3,l3,ao.x); ao.y = fmaf(b3,h3,ao.y);
      as.x = fmaf(a4,l4,as.x); as.y = fmaf(a4,h4,as.y);
      ao.x = fmaf(b4,l4,ao.x); ao.y = fmaf(b4,h4,ao.y);
      as.x = fmaf(a5,l5,as.x); as.y = fmaf(a5,h5,as.y);
      ao.x = fmaf(b5,l5,ao.x); ao.y = fmaf(b5,h5,ao.y);
      as.x = fmaf(a6,l6,as.x); as.y = fmaf(a6,h6,as.y);
      ao.x = fmaf(b6,l6,ao.x); ao.y = fmaf(b6,h6,ao.y);
      as.x = fmaf(a7,l7,as.x); as.y = fmaf(a7,h7,as.y);
      ao.x = fmaf(b7,l7,ao.x); ao.y = fmaf(b7,h7,ao.y);
    }
    for (; j < cnt; ++j){
      int   s0=__shfl(sl,j);
      float a0=__shfl(nsl,j), b0=__shfl(nol,j);
      u32 r0 = xb[(size_t)s0*64 + lane];
      float l0 = bf2f((u16)(r0&0xffff)), h0 = bf2f((u16)(r0>>16));
      as.x = fmaf(a0,l0,as.x); as.y = fmaf(a0,h0,as.y);
      ao.x = fmaf(b0,l0,ao.x); ao.y = fmaf(b0,h0,ao.y);
    }
  }
  ((u32*)out_s)[(size_t)wid*64 + lane] = (u32)f2bf(as.x) | ((u32)f2bf(as.y) << 16);
  ((u32*)out_o)[(size_t)wid*64 + lane] = (u32)f2bf(ao.x) | ((u32)f2bf(ao.y) << 16);
}

__global__ __launch_bounds__(256) void k_agg_one(
    const u16* __restrict__ h, const int* __restrict__ rp,
    const int* __restrict__ col, const float* __restrict__ dinv_o,
    u16* __restrict__ out, int n){
  int wid = (blockIdx.x * 256 + threadIdx.x) >> 6;
  int lane = threadIdx.x & 63;
  if (wid >= n) return;
  const u32* h2 = (const u32*)h;
  float dov = dinv_o[wid];
  u32 hv = h2[(size_t)wid*64 + lane];
  float oo = dov*dov;
  float2 ao = { bf2f((u16)(hv & 0xffff))*oo, bf2f((u16)(hv >> 16))*oo };
  int e0 = rp[wid], e1 = rp[wid+1];
  for (int base = e0; base < e1; base += 64){
    int cnt = e1 - base; if (cnt > 64) cnt = 64;
    int idx = base + (lane < cnt ? lane : cnt - 1);
    int   sl = col[idx];
    float nol = dinv_o[sl] * dov;
    int j = 0;
    for (; j + 8 <= cnt; j += 8){
      int s0=__shfl(sl,j),   s1=__shfl(sl,j+1), s2=__shfl(sl,j+2), s3=__shfl(sl,j+3);
      int s4=__shfl(sl,j+4), s5=__shfl(sl,j+5), s6=__shfl(sl,j+6), s7=__shfl(sl,j+7);
      u32 r0 = h2[(size_t)s0*64 + lane];
      u32 r1 = h2[(size_t)s1*64 + lane];
      u32 r2 = h2[(size_t)s2*64 + lane];
      u32 r3 = h2[(size_t)s3*64 + lane];
      u32 r4 = h2[(size_t)s4*64 + lane];
      u32 r5 = h2[(size_t)s5*64 + lane];
      u32 r6 = h2[(size_t)s6*64 + lane];
      u32 r7 = h2[(size_t)s7*64 + lane];
      float b0=__shfl(nol,j),   b1=__shfl(nol,j+1), b2=__shfl(nol,j+2), b3=__shfl(nol,j+3);
      float b4=__shfl(nol,j+4), b5=__shfl(nol,j+5), b6=__shfl(nol,j+6), b7=__shfl(nol,j+7);
      ao.x = fmaf(b0, bf2f((u16)(r0&0xffff)), ao.x); ao.y = fmaf(b0, bf2f((u16)(r0>>16)), ao.y);
      ao.x = fmaf(b1, bf2f((u16)(r1&0xffff)), ao.x); ao.y = fmaf(b1, bf2f((u16)(r1>>16)), ao.y);
      ao.x = fmaf(b2, bf2f((u16)(r2&0xffff)), ao.x); ao.y = fmaf(b2, bf2f((u16)(r2>>16)), ao.y);
      ao.x = fmaf(b3, bf2f((u16)(r3&0xffff)), ao.x); ao.y = fmaf(b3, bf2f((u16)(r3>>16)), ao.y);
      ao.x = fmaf(b4, bf2f((u16)(r4&0xffff)), ao.x); ao.y = fmaf(b4, bf2f((u16)(r4>>16)), ao.y);
      ao.x = fmaf(b5, bf2f((u16)(r5&0xffff)), ao.x); ao.y = fmaf(b5, bf2f((u16)(r5>>16)), ao.y);
      ao.x = fmaf(b6, bf2f((u16)(r6&0xffff)), ao.x); ao.y = fmaf(b6, bf2f((u16)(r6>>16)), ao.y);
      ao.x = fmaf(b7, bf2f((u16)(r7&0xffff)), ao.x); ao.y = fmaf(b7, bf2f((u16)(r7>>16)), ao.y);
    }
    for (; j < cnt; ++j){
      int   s0=__shfl(sl,j);
      float b0=__shfl(nol,j);
      u32 r0 = h2[(size_t)s0*64 + lane];
      ao.x = fmaf(b0, bf2f((u16)(r0&0xffff)), ao.x); ao.y = fmaf(b0, bf2f((u16)(r0>>16)), ao.y);
    }
  }
  ((u32*)out)[(size_t)wid*64 + lane] = (u32)f2bf(ao.x) | ((u32)f2bf(ao.y) << 16);
}

// ---------------- MFMA GEMMs: zero-LDS, 16-row blocks (best R16 config) -------
// Frags (16x16x32): A row=lane&15, k=(lane>>4)*8+j ; B col=lane&15 (Wt[col][k]);
// C/D col=lane&15, row=(lane>>4)*4+reg.

__global__ __launch_bounds__(256) void k_mfma_act2(
    const u16* __restrict__ A0, const u16* __restrict__ Wt0, const float* __restrict__ b0,
    const u16* __restrict__ A1, const u16* __restrict__ Wt1, const float* __restrict__ b1,
    const float* __restrict__ temb, const int* __restrict__ t_ptr,
    u16* __restrict__ out0, u16* __restrict__ out1, int n){
  const int sl = blockIdx.y;
  const u16* A  = sl ? A1 : A0;
  const u16* Wt = sl ? Wt1 : Wt0;
  const float* b = sl ? b1 : b0;
  u16* out = sl ? out1 : out0;
  const int tid = threadIdx.x;
  const int lane = tid & 63, wave = tid >> 6;
  const int lr = lane & 15, lg = lane >> 4;
  const int row0 = blockIdx.x * 16;
  int rowf = row0 + lr;
  int rowc = rowf < n ? rowf : n - 1;
  const char* Arow = (const char*)A + (size_t)rowc*256;
  const char* Wb   = (const char*)Wt + (wave*32 + lr)*256 + lg*16;
  bf16x8 af0 = *(const bf16x8*)(Arow + 0*64 + lg*16);
  bf16x8 af1 = *(const bf16x8*)(Arow + 1*64 + lg*16);
  bf16x8 af2 = *(const bf16x8*)(Arow + 2*64 + lg*16);
  bf16x8 af3 = *(const bf16x8*)(Arow + 3*64 + lg*16);
  f32x4 z = {0.f,0.f,0.f,0.f};
  f32x4 acc[2];
  acc[0] = z; acc[1] = z;
  #pragma unroll
  for (int cf = 0; cf < 2; ++cf){
    const char* wp = Wb + cf*16*256;
    acc[cf] = __builtin_amdgcn_mfma_f32_16x16x32_bf16(af0, *(const bf16x8*)(wp+0*64), acc[cf], 0,0,0);
    acc[cf] = __builtin_amdgcn_mfma_f32_16x16x32_bf16(af1, *(const bf16x8*)(wp+1*64), acc[cf], 0,0,0);
    acc[cf] = __builtin_amdgcn_mfma_f32_16x16x32_bf16(af2, *(const bf16x8*)(wp+2*64), acc[cf], 0,0,0);
    acc[cf] = __builtin_amdgcn_mfma_f32_16x16x32_bf16(af3, *(const bf16x8*)(wp+3*64), acc[cf], 0,0,0);
  }
  int t = sl ? *t_ptr : 0;
  int rbase = row0 + (lg << 2);
  #pragma unroll
  for (int cf = 0; cf < 2; ++cf){
    int colw = wave*32 + cf*16 + lr;
    float bb = b[colw];
    float tt = sl ? temb[t*128 + colw] : 0.f;
    #pragma unroll
    for (int r = 0; r < 4; ++r){
      int row = rbase + r;
      if (row < n)
        out[(size_t)row*128 + colw] = f2bf(fmaxf(acc[cf][r] + bb, 0.f) + tt);
    }
  }
}

__global__ __launch_bounds__(256) void k_mfma_quad(
    const u16* __restrict__ Apr, const u16* __restrict__ Aen,
    const u16* __restrict__ Wtpm, const float* __restrict__ bpm,
    const u16* __restrict__ Wtps, const float* __restrict__ bps,
    const u16* __restrict__ Wtmu, const float* __restrict__ bmu,
    const u16* __restrict__ Wtsd, const float* __restrict__ bsd,
    const u32* __restrict__ epsb,
    float* __restrict__ conf, float* __restrict__ pblk, int n){
  const int tid = threadIdx.x;
  const int lane = tid & 63, wave = tid >> 6;
  const int lr = lane & 15, lg = lane >> 4;
  const int row0 = blockIdx.x * 16;
  int rowf = row0 + lr;
  int rowc = rowf < n ? rowf : n - 1;
  const char* Ap = (const char*)Apr + (size_t)rowc*256;
  const char* Ae = (const char*)Aen + (size_t)rowc*256;
  const int wcb = (wave*32 + lr)*256 + lg*16;
  const char* Wpm = (const char*)Wtpm + wcb;
  const char* Wps = (const char*)Wtps + wcb;
  const char* Wmu = (const char*)Wtmu + wcb;
  const char* Wsd = (const char*)Wtsd + wcb;
  int rbase = row0 + (lg << 2);
  // prefetch eps + A fragments (latency off the MFMA chain)
  u32 ew[2][4];
  #pragma unroll
  for (int cf = 0; cf < 2; ++cf){
    int colw = wave*32 + cf*16 + lr;
    #pragma unroll
    for (int r = 0; r < 4; ++r){
      int row = rbase + r; if (row >= n) row = n - 1;
      ew[cf][r] = epsb[(size_t)row*64 + (colw >> 1)];
    }
  }
  bf16x8 ap0 = *(const bf16x8*)(Ap + 0*64 + lg*16);
  bf16x8 ap1 = *(const bf16x8*)(Ap + 1*64 + lg*16);
  bf16x8 ap2 = *(const bf16x8*)(Ap + 2*64 + lg*16);
  bf16x8 ap3 = *(const bf16x8*)(Ap + 3*64 + lg*16);
  bf16x8 ae0 = *(const bf16x8*)(Ae + 0*64 + lg*16);
  bf16x8 ae1 = *(const bf16x8*)(Ae + 1*64 + lg*16);
  bf16x8 ae2 = *(const bf16x8*)(Ae + 2*64 + lg*16);
  bf16x8 ae3 = *(const bf16x8*)(Ae + 3*64 + lg*16);
  f32x4 z = {0.f,0.f,0.f,0.f};
  f32x4 aPM[2], aPS[2], aMU[2], aSD[2];
  #pragma unroll
  for (int i = 0; i < 2; ++i){ aPM[i]=z; aPS[i]=z; aMU[i]=z; aSD[i]=z; }
  #pragma unroll
  for (int cf = 0; cf < 2; ++cf){
    int off = cf*16*256;
    aPM[cf] = __builtin_amdgcn_mfma_f32_16x16x32_bf16(ap0, *(const bf16x8*)(Wpm+off+0*64), aPM[cf], 0,0,0);
    aPM[cf] = __builtin_amdgcn_mfma_f32_16x16x32_bf16(ap1, *(const bf16x8*)(Wpm+off+1*64), aPM[cf], 0,0,0);
    aPM[cf] = __builtin_amdgcn_mfma_f32_16x16x32_bf16(ap2, *(const bf16x8*)(Wpm+off+2*64), aPM[cf], 0,0,0);
    aPM[cf] = __builtin_amdgcn_mfma_f32_16x16x32_bf16(ap3, *(const bf16x8*)(Wpm+off+3*64), aPM[cf], 0,0,0);
    aPS[cf] = __builtin_amdgcn_mfma_f32_16x16x32_bf16(ap0, *(const bf16x8*)(Wps+off+0*64), aPS[cf], 0,0,0);
    aPS[cf] = __builtin_amdgcn_mfma_f32_16x16x32_bf16(ap1, *(const bf16x8*)(Wps+off+1*64), aPS[cf], 0,0,0);
    aPS[cf] = __builtin_amdgcn_mfma_f32_16x16x32_bf16(ap2, *(const bf16x8*)(Wps+off+2*64), aPS[cf], 0,0,0);
    aPS[cf] = __builtin_amdgcn_mfma_f32_16x16x32_bf16(ap3, *(const bf16x8*)(Wps+off+3*64), aPS[cf], 0,0,0);
    aMU[cf] = __builtin_amdgcn_mfma_f32_16x16x32_bf16(ae0, *(const bf16x8*)(Wmu+off+0*64), aMU[cf], 0,0,0);
    aMU[cf] = __builtin_amdgcn_mfma_f32_16x16x32_bf16(ae1, *(const bf16x8*)(Wmu+off+1*64), aMU[cf], 0,0,0);
    aMU[cf] = __builtin_amdgcn_mfma_f32_16x16x32_bf16(ae2, *(const bf16x8*)(Wmu+off+2*64), aMU[cf], 0,0,0);
    aMU[cf] = __builtin_amdgcn_mfma_f32_16x16x32_bf16(ae3, *(const bf16x8*)(Wmu+off+3*64), aMU[cf], 0,0,0);
    aSD[cf] = __builtin_amdgcn_mfma_f32_16x16x32_bf16(ae0, *(const bf16x8*)(Wsd+off+0*64), aSD[cf], 0,0,0);
    aSD[cf] = __builtin_amdgcn_mfma_f32_16x16x32_bf16(ae1, *(const bf16x8*)(Wsd+off+1*64), aSD[cf], 0,0,0);
    aSD[cf] = __builtin_amdgcn_mfma_f32_16x16x32_bf16(ae2, *(const bf16x8*)(Wsd+off+2*64), aSD[cf], 0,0,0);
    aSD[cf] = __builtin_amdgcn_mfma_f32_16x16x32_bf16(ae3, *(const bf16x8*)(Wsd+off+3*64), aSD[cf], 0,0,0);
  }
  const float EPS = 1e-9f;
  float klsum = 0.f;
  #pragma unroll
  for (int cf = 0; cf < 2; ++cf){
    int colw = wave*32 + cf*16 + lr;
    float bb1 = bpm[colw], bb2 = bps[colw];
    float bb3 = bmu[colw], bb4 = bsd[colw];
    #pragma unroll
    for (int r = 0; r < 4; ++r){
      int row = rbase + r;
      if (row < n){
        size_t m = (size_t)row*128 + colw;
        float pmv = aPM[cf][r] + bb1;
        float psv = sigmoidf_(aPS[cf][r] + bb2);
        float em  = aMU[cf][r] + bb3;
        float es  = sigmoidf_(aSD[cf][r] + bb4);
        float eps = bf2f((u16)((colw & 1) ? (ew[cf][r] >> 16) : (ew[cf][r] & 0xffff)));
        __builtin_nontemporal_store(fmaf(eps, es, em), &conf[m]);   // never re-read
        float es_e = es + EPS, ps_e = psv + EPS;
        float diff = em - pmv;
        klsum += 2.0f*__logf(ps_e/es_e)
               + (es_e*es_e + diff*diff) / (ps_e*ps_e) - 1.0f;
      }
    }
  }
  #pragma unroll
  for (int off = 32; off > 0; off >>= 1) klsum += __shfl_down(klsum, off);
  __shared__ float wsum[4];
  if ((tid & 63) == 0) wsum[tid >> 6] = klsum;
  __syncthreads();
  if (tid == 0) pblk[blockIdx.x] = wsum[0] + wsum[1] + wsum[2] + wsum[3];
}

__global__ __launch_bounds__(256) void k_finish(const float* __restrict__ pblk, int nb,
                                                float* __restrict__ out0, int n){
  __shared__ double sh[256];
  double s = 0.0;
  for (int i = threadIdx.x; i < nb; i += 256) s += (double)pblk[i];
  sh[threadIdx.x] = s; __syncthreads();
  for (int off = 128; off > 0; off >>= 1){
    if (threadIdx.x < off) sh[threadIdx.x] += sh[threadIdx.x + off];
    __syncthreads();
  }
  if (threadIdx.x == 0) out0[0] = (float)(0.5 * sh[0] / (double)n);
}

// ---------------------------------------------------------------------------
extern "C" void kernel_launch(void* const* d_in, const int* in_sizes, int n_in,
                              void* d_out, int out_size, void* d_ws, size_t ws_size,
                              hipStream_t stream){
  const void*  eidx   = d_in[0];
  const float* x      = (const float*)d_in[1];
  const int*   t_ptr  = (const int*)d_in[2];
  const float* escore = (const float*)d_in[3];
  const float* W_enc = (const float*)d_in[6];  const float* b_enc = (const float*)d_in[7];
  const float* W_mu  = (const float*)d_in[8];  const float* b_mu  = (const float*)d_in[9];
  const float* W_std = (const float*)d_in[10]; const float* b_std = (const float*)d_in[11];
  const float* W_pr  = (const float*)d_in[12]; const float* b_pr  = (const float*)d_in[13];
  const float* W_pm  = (const float*)d_in[14]; const float* b_pm  = (const float*)d_in[15];
  const float* W_ps  = (const float*)d_in[16]; const float* b_ps  = (const float*)d_in[17];
  const float* temb  = (const float*)d_in[18];

  const int N = in_sizes[1] / D;
  const int E = in_sizes[3];

  char* w = (char*)d_ws;
  auto alloc = [&](size_t bytes) -> char* {
    char* p = w; w += (bytes + 255) & ~(size_t)255; return p;
  };
  int*    flag   = (int*)   alloc(256);
  int*    src_w  = (int*)   alloc((size_t)E*4);
  int*    dst_w  = (int*)   alloc((size_t)E*4);
  int*    cnt    = (int*)   alloc((size_t)N*4);
  int*    rp     = (int*)   alloc((size_t)(N+1)*4);
  int*    cur    = (int*)   alloc((size_t)N*4);
  float*  dinv_s = (float*) alloc((size_t)N*4);
  float*  dinv_o = (float*) alloc((size_t)N*4);
  int*    bsum   = (int*)   alloc(1024*4);
  int*    col    = (int*)   alloc((size_t)E*4);
  float*  wsrt   = (float*) alloc((size_t)E*4);
  u16*    wt     = (u16*)   alloc((size_t)6*16384*2);  // 6 transposed bf16 weights
  u32*    XB     = (u32*)   alloc((size_t)N*64*4);     // bf16x2-packed x
  u16*    B1     = (u16*)   alloc((size_t)N*D*2);  // agg_score_x (bf16)
  u16*    B2     = (u16*)   alloc((size_t)N*D*2);  // agg_ones_x -> agg_ones_enc
  u16*    B3     = (u16*)   alloc((size_t)N*D*2);  // enc_t
  u16*    B5     = (u16*)   alloc((size_t)N*D*2);  // prior
  u32*    EPSB   = (u32*)   alloc((size_t)N*64*4); // bf16x2-packed eps
  const int gG16 = (N + 15) / 16;                  // MFMA tiles (16 rows)
  float*  pblk   = (float*) alloc((size_t)gG16*4);
  (void)ws_size; (void)n_in; (void)out_size;

  float* conf = ((float*)d_out) + 1;

  u16* Wt_enc = wt + 0*16384;
  u16* Wt_pr  = wt + 1*16384;
  u16* Wt_pm  = wt + 2*16384;
  u16* Wt_ps  = wt + 3*16384;
  u16* Wt_mu  = wt + 4*16384;
  u16* Wt_std = wt + 5*16384;

  const int gE  = (E + 255) / 256;
  const int gN  = (N + 255) / 256;
  const int gW  = (N * 64 + 255) / 256;

  // prep: detect + init(cnt) + wconv + xconv + eps, one launch (grid-stride)
  k_prep   <<<2048, 256, 0, stream>>>((const u32*)eidx, flag,
                                      W_enc, W_pr, W_pm, W_ps, W_mu, W_std, wt,
                                      x, XB, EPSB, cnt, N, N*64);
  k_norm   <<<gE, 256, 0, stream>>>(eidx, flag, src_w, dst_w, cnt, E);
  k_scan1  <<<gN, 256, 0, stream>>>(cnt, rp, bsum, N);
  k_scan2  <<<1, 1024, 0, stream>>>(bsum, gN);
  k_scan3  <<<gN, 256, 0, stream>>>(rp, cur, bsum, cnt, dinv_o, N, E);
  k_scatter<<<gE, 256, 0, stream>>>(src_w, dst_w, escore, cur, col, wsrt, E);
  k_deg    <<<gN, 256, 0, stream>>>(rp, wsrt, dinv_s, N);

  // agg_sx -> B1 (bf16) ; agg_ox -> B2 (bf16)
  k_agg_dual<<<gW, 256, 0, stream>>>(XB, rp, col, wsrt, dinv_s, dinv_o, B1, B2, N);
  // y=0: enc_t = relu(B1@Wenc+b) -> B3 ; y=1: prior = relu(B2@Wpr+b)+temb -> B5
  k_mfma_act2<<<dim3(gG16,2), 256, 0, stream>>>(B1, Wt_enc, b_enc, B2, Wt_pr, b_pr,
                                                temb, t_ptr, B3, B5, N);
  // agg_oe = A_ones enc_t -> B2 (bf16 gather)
  k_agg_one<<<gW, 256, 0, stream>>>(B3, rp, col, dinv_o, B2, N);
  // pm/ps/em/es + conf + kl partials, fused
  k_mfma_quad<<<gG16, 256, 0, stream>>>(B5, B2, Wt_pm, b_pm, Wt_ps, b_ps,
                                        Wt_mu, b_mu, Wt_std, b_std, EPSB,
                                        conf, pblk, N);
  k_finish<<<1, 256, 0, stream>>>(pblk, gG16, (float*)d_out, N);
}